// Round 1
// baseline (527.583 us; speedup 1.0000x reference)
//
#include <hip/hip_runtime.h>
#include <hip/hip_bf16.h>

#define T_TOK 1024
#define H_DIM 1024
#define E_NUM 64
#define I_DIM 512
#define K_TOP 8
#define TG_NUM 4
#define CAPC 512
#define RSCALE 2.5f

typedef __attribute__((ext_vector_type(8))) short bf16x8;
typedef __attribute__((ext_vector_type(4))) float f32x4;

__device__ __forceinline__ ushort f2bf(float f) {
    union { float f; unsigned u; } v; v.f = f;
    unsigned r = v.u + 0x7fffu + ((v.u >> 16) & 1u);   // round-to-nearest-even
    return (ushort)(r >> 16);
}

// ---------------- router ----------------
__global__ __launch_bounds__(256) void k_router(
    const float* __restrict__ x, const float* __restrict__ rw,
    int* __restrict__ cnt, int* __restrict__ exp_tok,
    int* __restrict__ tslot, float* __restrict__ tw)
{
    const int t    = blockIdx.x;
    const int lane = threadIdx.x & 63;
    const int w    = threadIdx.x >> 6;

    const float* xp = x + (size_t)t * H_DIM + w * 256;
    const float* wp = rw + (size_t)(w * 256) * E_NUM + lane;
    float acc = 0.f;
    #pragma unroll 8
    for (int i = 0; i < 256; ++i)
        acc += xp[i] * wp[(size_t)i * E_NUM];

    __shared__ float part[4][64];
    part[w][lane] = acc;
    __syncthreads();
    if (threadIdx.x >= 64) return;

    float logit = part[0][lane] + part[1][lane] + part[2][lane] + part[3][lane];
    float score = 1.f / (1.f + expf(-logit));

    // group max over 8-lane groups (G=8 groups of 8 experts)
    float gm = score;
    gm = fmaxf(gm, __shfl_xor(gm, 1));
    gm = fmaxf(gm, __shfl_xor(gm, 2));
    gm = fmaxf(gm, __shfl_xor(gm, 4));
    const int myg = lane >> 3;
    int grank = 0;
    #pragma unroll
    for (int j = 0; j < 8; ++j) {
        float gj = __shfl(gm, j * 8);
        grank += (gj > gm) || (gj == gm && j < myg);
    }
    float masked = (grank < TG_NUM) ? score : 0.f;

    // rank among 64 experts (stable: lower index wins ties)
    int erank = 0;
    for (int j = 0; j < 64; ++j) {
        float sj = __shfl(masked, j);
        erank += (sj > masked) || (sj == masked && j < lane);
    }
    const bool keep = (erank < K_TOP);

    float kv = keep ? masked : 0.f;
    kv += __shfl_xor(kv, 1);  kv += __shfl_xor(kv, 2);  kv += __shfl_xor(kv, 4);
    kv += __shfl_xor(kv, 8);  kv += __shfl_xor(kv, 16); kv += __shfl_xor(kv, 32);
    const float wgt = masked / fmaxf(kv, 1e-9f) * RSCALE;

    if (keep) {
        int slot = atomicAdd(&cnt[lane], 1);
        if (slot < CAPC) {
            exp_tok[lane * CAPC + slot] = t;
            tslot[t * K_TOP + erank] = (lane << 9) | slot;
            tw[t * K_TOP + erank]    = wgt;
        } else {
            tslot[t * K_TOP + erank] = (lane << 9);
            tw[t * K_TOP + erank]    = 0.f;
        }
    }
}

// ---------------- prefix scan of counts ----------------
__global__ void k_scan(const int* __restrict__ cnt, int* __restrict__ offs)
{
    const int lane = threadIdx.x;   // 64 threads
    int v = min(cnt[lane], CAPC);
    #pragma unroll
    for (int off = 1; off < 64; off <<= 1) {
        int u = __shfl_up(v, off);
        if (lane >= off) v += u;
    }
    offs[lane + 1] = v;             // inclusive scan -> offs[1..64]
    if (lane == 0) offs[0] = 0;
}

// ---------------- GEMM 1: gate & up + SwiGLU ----------------
// grid: x = I/64 (8), y = E+1 (65; 64 == shared expert), z = 4 M-tiles of 256
__global__ __launch_bounds__(512) void k_gemm1(
    const float* __restrict__ x,
    const float* __restrict__ gate_w, const float* __restrict__ up_w,
    const float* __restrict__ sgate_w, const float* __restrict__ sup_w,
    const int* __restrict__ cnt, const int* __restrict__ offs,
    const int* __restrict__ exp_tok,
    ushort* __restrict__ hbuf)
{
    const int e  = blockIdx.y;
    const int nb = blockIdx.x;
    const int mt = blockIdx.z;
    const bool sh = (e == E_NUM);
    const int Me = sh ? T_TOK : min(cnt[e], CAPC);
    const int m0 = mt * 256;
    if (m0 >= Me) return;
    const int Mt   = min(256, Me - m0);
    const int base = offs[e];
    const float* gw = sh ? sgate_w : gate_w + (size_t)e * H_DIM * I_DIM;
    const float* uw = sh ? sup_w  : up_w  + (size_t)e * H_DIM * I_DIM;
    const int n0 = nb * 64;

    __shared__ ushort As[256 * 40];   // 256 x 32 bf16, stride 40 (pad)
    __shared__ ushort Bg[64 * 40];
    __shared__ ushort Bu[64 * 40];

    const int tid  = threadIdx.x;
    const int kq   = tid & 7;          // A: float4 chunk in K (0..7)
    const int arow = tid >> 3;         // A: base row (0..63), +64*i
    const int bn   = tid & 63;         // B: column
    const int bks  = tid >> 6;         // B: k-quad (0..7)

    int tokens[4];
    #pragma unroll
    for (int i = 0; i < 4; ++i) {
        int l = arow + 64 * i;
        tokens[i] = (l < Mt) ? (sh ? (m0 + l) : exp_tok[e * CAPC + m0 + l]) : -1;
    }

    const int lane = tid & 63;
    const int wid  = tid >> 6;
    const int wm = wid >> 1, wn = wid & 1;    // 4 x 2 wave grid
    const int fr = lane & 15, fg = lane >> 4;

    f32x4 accg[4][2], accu[4][2];
    #pragma unroll
    for (int a = 0; a < 4; ++a)
        #pragma unroll
        for (int b = 0; b < 2; ++b) { accg[a][b] = (f32x4)0.f; accu[a][b] = (f32x4)0.f; }

    for (int kt = 0; kt < H_DIM / 32; ++kt) {
        // stage A (with gather + fp32->bf16)
        #pragma unroll
        for (int i = 0; i < 4; ++i) {
            int l = arow + 64 * i;
            ushort4 v4;
            if (tokens[i] >= 0) {
                const float4 g = *(const float4*)&x[(size_t)tokens[i] * H_DIM + kt * 32 + kq * 4];
                v4.x = f2bf(g.x); v4.y = f2bf(g.y); v4.z = f2bf(g.z); v4.w = f2bf(g.w);
            } else { v4.x = v4.y = v4.z = v4.w = 0; }
            *(ushort4*)&As[l * 40 + kq * 4] = v4;
        }
        // stage B gate & up (transpose: 4 consecutive k for column bn)
        {
            int kk = kt * 32 + bks * 4;
            ushort4 vg, vu;
            #pragma unroll
            for (int j = 0; j < 4; ++j) {
                ((ushort*)&vg)[j] = f2bf(gw[(size_t)(kk + j) * I_DIM + n0 + bn]);
                ((ushort*)&vu)[j] = f2bf(uw[(size_t)(kk + j) * I_DIM + n0 + bn]);
            }
            *(ushort4*)&Bg[bn * 40 + bks * 4] = vg;
            *(ushort4*)&Bu[bn * 40 + bks * 4] = vu;
        }
        __syncthreads();

        bf16x8 afr[4], bgf[2], buf[2];
        #pragma unroll
        for (int fm = 0; fm < 4; ++fm)
            afr[fm] = *(const bf16x8*)&As[(wm * 64 + fm * 16 + fr) * 40 + fg * 8];
        #pragma unroll
        for (int fn = 0; fn < 2; ++fn) {
            bgf[fn] = *(const bf16x8*)&Bg[(wn * 32 + fn * 16 + fr) * 40 + fg * 8];
            buf[fn] = *(const bf16x8*)&Bu[(wn * 32 + fn * 16 + fr) * 40 + fg * 8];
        }
        #pragma unroll
        for (int fm = 0; fm < 4; ++fm)
            #pragma unroll
            for (int fn = 0; fn < 2; ++fn) {
                accg[fm][fn] = __builtin_amdgcn_mfma_f32_16x16x32_bf16(afr[fm], bgf[fn], accg[fm][fn], 0, 0, 0);
                accu[fm][fn] = __builtin_amdgcn_mfma_f32_16x16x32_bf16(afr[fm], buf[fn], accu[fm][fn], 0, 0, 0);
            }
        __syncthreads();
    }

    // epilogue: h = silu(g) * u -> bf16
    #pragma unroll
    for (int fm = 0; fm < 4; ++fm)
        #pragma unroll
        for (int fn = 0; fn < 2; ++fn)
            #pragma unroll
            for (int r = 0; r < 4; ++r) {
                int l = wm * 64 + fm * 16 + fg * 4 + r;
                if (l < Mt) {
                    float g = accg[fm][fn][r];
                    float u = accu[fm][fn][r];
                    float h = g / (1.f + expf(-g)) * u;
                    hbuf[(size_t)(base + m0 + l) * I_DIM + n0 + wn * 32 + fn * 16 + fr] = f2bf(h);
                }
            }
}

// ---------------- GEMM 2: down ----------------
// grid: x = H/64 (16), y = 65, z = 4
__global__ __launch_bounds__(512) void k_gemm2(
    const ushort* __restrict__ hbuf,
    const float* __restrict__ down_w, const float* __restrict__ sdown_w,
    const int* __restrict__ cnt, const int* __restrict__ offs,
    float* __restrict__ obuf)
{
    const int e  = blockIdx.y;
    const int nb = blockIdx.x;
    const int mt = blockIdx.z;
    const bool sh = (e == E_NUM);
    const int Me = sh ? T_TOK : min(cnt[e], CAPC);
    const int m0 = mt * 256;
    if (m0 >= Me) return;
    const int Mt   = min(256, Me - m0);
    const int base = offs[e];
    const float* dw = sh ? sdown_w : down_w + (size_t)e * I_DIM * H_DIM;
    const int n0 = nb * 64;

    __shared__ ushort As[256 * 40];
    __shared__ ushort Bt[64 * 40];

    const int tid = threadIdx.x;
    const int bn  = tid & 63;
    const int bks = tid >> 6;
    const int lane = tid & 63;
    const int wid  = tid >> 6;
    const int wm = wid >> 1, wn = wid & 1;
    const int fr = lane & 15, fg = lane >> 4;

    f32x4 acc[4][2];
    #pragma unroll
    for (int a = 0; a < 4; ++a)
        #pragma unroll
        for (int b = 0; b < 2; ++b) acc[a][b] = (f32x4)0.f;

    for (int kt = 0; kt < I_DIM / 32; ++kt) {
        // stage A (bf16 direct copy)
        #pragma unroll
        for (int i = 0; i < 2; ++i) {
            int c = tid + 512 * i;
            int l = c >> 2, kq8 = c & 3;
            uint4 v = make_uint4(0u, 0u, 0u, 0u);
            if (l < Mt) v = *(const uint4*)&hbuf[(size_t)(base + m0 + l) * I_DIM + kt * 32 + kq8 * 8];
            *(uint4*)&As[l * 40 + kq8 * 8] = v;
        }
        // stage B
        {
            int kk = kt * 32 + bks * 4;
            ushort4 vd;
            #pragma unroll
            for (int j = 0; j < 4; ++j)
                ((ushort*)&vd)[j] = f2bf(dw[(size_t)(kk + j) * H_DIM + n0 + bn]);
            *(ushort4*)&Bt[bn * 40 + bks * 4] = vd;
        }
        __syncthreads();

        bf16x8 afr[4], bfr[2];
        #pragma unroll
        for (int fm = 0; fm < 4; ++fm)
            afr[fm] = *(const bf16x8*)&As[(wm * 64 + fm * 16 + fr) * 40 + fg * 8];
        #pragma unroll
        for (int fn = 0; fn < 2; ++fn)
            bfr[fn] = *(const bf16x8*)&Bt[(wn * 32 + fn * 16 + fr) * 40 + fg * 8];
        #pragma unroll
        for (int fm = 0; fm < 4; ++fm)
            #pragma unroll
            for (int fn = 0; fn < 2; ++fn)
                acc[fm][fn] = __builtin_amdgcn_mfma_f32_16x16x32_bf16(afr[fm], bfr[fn], acc[fm][fn], 0, 0, 0);
        __syncthreads();
    }

    #pragma unroll
    for (int fm = 0; fm < 4; ++fm)
        #pragma unroll
        for (int fn = 0; fn < 2; ++fn)
            #pragma unroll
            for (int r = 0; r < 4; ++r) {
                int l = wm * 64 + fm * 16 + fg * 4 + r;
                if (l < Mt)
                    obuf[(size_t)(base + m0 + l) * H_DIM + n0 + wn * 32 + fn * 16 + fr] = acc[fm][fn][r];
            }
}

// ---------------- combine ----------------
__global__ __launch_bounds__(256) void k_combine(
    const float* __restrict__ obuf, const int* __restrict__ offs,
    const int* __restrict__ tslot, const float* __restrict__ tw,
    float* __restrict__ out)
{
    const int t = blockIdx.x;
    __shared__ int   rs[8];
    __shared__ float wss[8];
    if (threadIdx.x < 8) {
        int id = tslot[t * K_TOP + threadIdx.x];
        rs[threadIdx.x]  = offs[id >> 9] + (id & 511);
        wss[threadIdx.x] = tw[t * K_TOP + threadIdx.x];
    }
    __syncthreads();
    const int c = threadIdx.x * 4;
    const int shrow = offs[64] + t;
    float4 acc = *(const float4*)&obuf[(size_t)shrow * H_DIM + c];
    #pragma unroll
    for (int j = 0; j < 8; ++j) {
        float4 v = *(const float4*)&obuf[(size_t)rs[j] * H_DIM + c];
        float w = wss[j];
        acc.x += w * v.x; acc.y += w * v.y; acc.z += w * v.z; acc.w += w * v.w;
    }
    *(float4*)&out[(size_t)t * H_DIM + c] = acc;
}

extern "C" void kernel_launch(void* const* d_in, const int* in_sizes, int n_in,
                              void* d_out, int out_size, void* d_ws, size_t ws_size,
                              hipStream_t stream)
{
    const float* x       = (const float*)d_in[0];
    const float* rw      = (const float*)d_in[1];
    const float* gate_w  = (const float*)d_in[2];
    const float* up_w    = (const float*)d_in[3];
    const float* down_w  = (const float*)d_in[4];
    const float* sgate_w = (const float*)d_in[5];
    const float* sup_w   = (const float*)d_in[6];
    const float* sdown_w = (const float*)d_in[7];
    float* out = (float*)d_out;

    char* ws = (char*)d_ws;
    int*   cnt     = (int*)(ws + 0);                 // 64 ints
    int*   offs    = (int*)(ws + 256);               // 65 ints
    int*   exp_tok = (int*)(ws + 1024);              // 64*512 ints = 128 KB
    int*   tslot   = (int*)(ws + 1024 + 131072);     // 8192 ints
    float* tw      = (float*)(ws + 1024 + 131072 + 32768);
    ushort* hbuf   = (ushort*)(ws + (1 << 18));                   // 9216 x 512 bf16  (~9.4 MB)
    float*  obuf   = (float*)(ws + (16u << 20));                  // 9216 x 1024 f32  (~36 MB)

    hipMemsetAsync(cnt, 0, 256, stream);
    k_router<<<T_TOK, 256, 0, stream>>>(x, rw, cnt, exp_tok, tslot, tw);
    k_scan<<<1, 64, 0, stream>>>(cnt, offs);
    k_gemm1<<<dim3(8, E_NUM + 1, 4), 512, 0, stream>>>(x, gate_w, up_w, sgate_w, sup_w,
                                                       cnt, offs, exp_tok, hbuf);
    k_gemm2<<<dim3(16, E_NUM + 1, 4), 512, 0, stream>>>(hbuf, down_w, sdown_w, cnt, offs, obuf);
    k_combine<<<T_TOK, 256, 0, stream>>>(obuf, offs, tslot, tw, out);
}